// Round 17
// baseline (905.296 us; speedup 1.0000x reference)
//
#include <hip/hip_runtime.h>
#include <hip/hip_bf16.h>

// ---------------------------------------------------------------------------
// WeightOnlyLinear: y = x @ dequant4(qweight, scales, qzeros) + bias
//   x (8192,4096) fp32 | scales (32,12288) | bias (12288) | qweight (512,12288)
//   qzeros (32,1536) | out (8192,12288) fp32
// R17: R16 co-resident structure (tile 256x128, 8 waves 2Mx4N, wave 128x32,
//   ring-3 x 24KB LDS, launch_bounds(512,4) -> 2 blocks/CU) with the MFMA
//   shape switched to 32x32x16 (faster pipe: 2495 vs 2176 TF ceiling; half
//   the MFMA instructions -> fewer issue slots). Fragment-major maps are the
//   R8-R10-verified 32x32 ones. Ledger unchanged: per K-32 phase
//   {vm3; bar; 10 frag reads; stage(q+2) [3 gloads]; 8 MFMA}; tail vm3/vm0.
// ---------------------------------------------------------------------------

typedef __attribute__((ext_vector_type(8))) short short8;
typedef __attribute__((ext_vector_type(4))) float f32x4;
typedef __attribute__((ext_vector_type(16))) float f32x16;

__device__ __forceinline__ short f2bf(float f) {
  unsigned u = __float_as_uint(f);
  u += 0x7fffu + ((u >> 16) & 1u);
  return (short)(u >> 16);
}

__device__ __forceinline__ void gload_lds16(const void* g, void* l) {
  __builtin_amdgcn_global_load_lds(
      (const __attribute__((address_space(1))) void*)g,
      (__attribute__((address_space(3))) void*)l,
      16, 0, 0);
}

__device__ __forceinline__ void bar() {
  asm volatile("" ::: "memory");
  __builtin_amdgcn_s_barrier();
  asm volatile("" ::: "memory");
}
__device__ __forceinline__ void wait_vm3() {
  asm volatile("s_waitcnt vmcnt(3)" ::: "memory");
}
__device__ __forceinline__ void wait_vm0() {
  asm volatile("s_waitcnt vmcnt(0)" ::: "memory");
}

// ---------------------------------------------------------------------------
// Pass 1 (R17): dequant qweight -> B' fragment-major (nb128, kt32) 8KB tiles,
// 32x32x16 frag layout. Chunk c (16B, 0..511): cb=c>>7, kh=(c>>6)&1,
// kq2=(c>>5)&1, l=c&31; col = nb*128 + cb*32 + l; k8 = kh*2+kq2;
// kw = kt*4 + k8. One qweight word == one chunk.
// grid = (N/128)*(K/32), 256 thr, 2 chunks/thr.
// ---------------------------------------------------------------------------
__global__ __launch_bounds__(256) void dequant_tile_kernel(
    const int* __restrict__ qweight, const int* __restrict__ qzeros,
    const float* __restrict__ scales, short* __restrict__ Bt,
    int N, int K) {
  const int ktn = K >> 5;
  const int bx = blockIdx.x;
  const int nb = bx / ktn, kt = bx - nb * ktn;
  const int t = threadIdx.x;
  const int g = kt >> 2;  // GROUPSIZE=128 = 4 k32-tiles
  char* dst = (char*)Bt + (size_t)bx * 8192;
#pragma unroll
  for (int p = 0; p < 2; ++p) {
    const int c = p * 256 + t;
    const int n = nb * 128 + (c >> 7) * 32 + (c & 31);
    const int k8 = ((c >> 6) & 1) * 2 + ((c >> 5) & 1);
    const int kw = kt * 4 + k8;
    const float sc = scales[(size_t)g * N + n];
    const int zw = qzeros[(size_t)g * (N >> 3) + (n >> 3)];
    const float zs = -(float)(((zw >> ((n & 7) * 4)) & 15) + 1) * sc;
    const int w = qweight[(size_t)kw * N + n];
    short8 v;
#pragma unroll
    for (int e = 0; e < 8; ++e)
      v[e] = f2bf(fmaf((float)((w >> (4 * e)) & 15), sc, zs));
    *(short8*)(dst + c * 16) = v;
  }
}

// ---------------------------------------------------------------------------
// Pass 2 (R17): x fp32 -> A' fragment-major (mb256, kt32) 16KB tiles,
// 32x32x16 frag layout. Chunk c (0..1023): rb=c>>7, kh=(c>>6)&1,
// kq2=(c>>5)&1, l=c&31; row = mb*256 + rb*32 + l; k = kt*32 + kh*16 + kq2*8.
// grid = (M/256)*(K/32), 256 thr, 4 chunks/thr.
// ---------------------------------------------------------------------------
__global__ __launch_bounds__(256) void cvt_tile_kernel(
    const float* __restrict__ x, short* __restrict__ xb, int K) {
  const int ktn = K >> 5;
  const int bx = blockIdx.x;
  const int mb = bx / ktn, kt = bx - mb * ktn;
  char* dst = (char*)xb + (size_t)bx * 16384;
#pragma unroll
  for (int p = 0; p < 4; ++p) {
    const int c = p * 256 + threadIdx.x;
    const int row = mb * 256 + (c >> 7) * 32 + (c & 31);
    const int k = kt * 32 + ((c >> 6) & 1) * 16 + ((c >> 5) & 1) * 8;
    const float* s = x + (size_t)row * K + k;
    float4 f0 = *(const float4*)s;
    float4 f1 = *(const float4*)(s + 4);
    short8 v;
    v[0] = f2bf(f0.x); v[1] = f2bf(f0.y); v[2] = f2bf(f0.z); v[3] = f2bf(f0.w);
    v[4] = f2bf(f1.x); v[5] = f2bf(f1.y); v[6] = f2bf(f1.z); v[7] = f2bf(f1.w);
    *(short8*)(dst + c * 16) = v;
  }
}

// ---------------------------------------------------------------------------
// Pass 3 (R17): 256x128 GEMM, 512 threads = 8 waves (2M x 4N), wave 128x32.
// MFMA 32x32x16; acc f32x16[4] (wave = 4x1 frags of 32x32).
// LDS: ring-3 x 24576 (A 16KB @0, B 8KB @16384), fragment-major.
// Phase q (slot q%3): {vm3; bar; 10 frag reads; stage tile q+2 ->
// slot (q+2)%3 [3 gloads]; setprio 8 MFMA}. Tail peel: vm3 / vm0.
// ---------------------------------------------------------------------------
#define GBM 256
#define GBN 128

__global__ __launch_bounds__(512, 4) void gemm256_kernel(
    const short* __restrict__ At, const short* __restrict__ Bt,
    const float* __restrict__ bias, float* __restrict__ C,
    int M, int N, int K) {
  __shared__ __align__(16) char lds[3 * 24576];
  const int tid = threadIdx.x;
  const int nbx = N / GBN;
  const int nwg = gridDim.x;
  int bid = blockIdx.x;
  if ((nwg & 7) == 0) bid = (bid & 7) * (nwg >> 3) + (bid >> 3);  // T1
  const int mb = bid / nbx;
  const int nb = bid % nbx;
  const int bm = mb * GBM, bn = nb * GBN;

  const int wid = tid >> 6, lane = tid & 63;
  const int wr = wid >> 2, wc = wid & 3;  // 2x4 wave grid
  const int l31 = lane & 31;
  const int lq2 = lane >> 5;

  const int P = K >> 5;  // K-32 tiles; launcher guarantees (P-2)%3==0

  char* lb = &lds[0];

  // frag read bases: A frag (rb = wr*4 + i, kh) at
  //   SL*24576 + rb*2048 + kh*1024 + lane*16; B frag (cb = wc, kh) at
  //   16384 + SL*24576 + wc*2048 + kh*1024 + lane*16.
  const char* aBase = lb + wr * 8192 + lane * 16;
  const char* bBase = lb + 16384 + wc * 2048 + lane * 16;

  // staging: A chunks {tid, tid+512}, B chunk {tid}; linear dst
  const char* pA = (const char*)At + (size_t)mb * P * 16384 + (size_t)tid * 16;
  const char* pB = (const char*)Bt + (size_t)nb * P * 8192 + (size_t)tid * 16;
  char* dA = lb + tid * 16;
  char* dB = lb + 16384 + tid * 16;

#define STAGE(TSL, AOFF, BOFF)                                \
  do {                                                        \
    gload_lds16(pA + (AOFF), dA + (TSL)*24576);               \
    gload_lds16(pA + (AOFF) + 8192, dA + (TSL)*24576 + 8192); \
    gload_lds16(pB + (BOFF), dB + (TSL)*24576);               \
  } while (0)

  short8 aR[4][2], bR[2];

#define RD(SL)                                                            \
  do {                                                                    \
    _Pragma("unroll") for (int i = 0; i < 4; ++i)                         \
        _Pragma("unroll") for (int kh = 0; kh < 2; ++kh) aR[i][kh] =      \
        *(const short8*)(aBase + (SL)*24576 + i * 2048 + kh * 1024);      \
    _Pragma("unroll") for (int kh = 0; kh < 2; ++kh) bR[kh] =             \
        *(const short8*)(bBase + (SL)*24576 + kh * 1024);                 \
  } while (0)

  f32x16 acc[4] = {};

#define MFMA8()                                                           \
  do {                                                                    \
    __builtin_amdgcn_s_setprio(1);                                        \
    _Pragma("unroll") for (int kh = 0; kh < 2; ++kh)                      \
        _Pragma("unroll") for (int i = 0; i < 4; ++i) acc[i] =            \
            __builtin_amdgcn_mfma_f32_32x32x16_bf16(aR[i][kh], bR[kh],    \
                                                    acc[i], 0, 0, 0);     \
    __builtin_amdgcn_s_setprio(0);                                        \
  } while (0)

  // prologue: tile0 -> slot0, tile1 -> slot1 (6 gloads)
  STAGE(0, 0, 0);
  STAGE(1, 16384, 8192);

  // body: (P-2)/3 iterations x 3 phases; phase q stages tile q+2.
  const int nIt = (P - 2) / 3;
  for (int it = 0; it < nIt; ++it) {
    wait_vm3(); bar();
    RD(0); STAGE(2, 2 * 16384, 2 * 8192); MFMA8();
    wait_vm3(); bar();
    RD(1); STAGE(0, 3 * 16384, 3 * 8192); MFMA8();
    wait_vm3(); bar();
    RD(2); STAGE(1, 4 * 16384, 4 * 8192); MFMA8();
    pA += 3 * 16384;
    pB += 3 * 8192;
  }
  // peel: q = P-2 (slot 0), q = P-1 (slot 1)
  wait_vm3(); bar();
  RD(0); MFMA8();
  wait_vm0(); bar();
  RD(1); MFMA8();

#undef MFMA8
#undef RD
#undef STAGE

  // epilogue: C = acc + bias.
  // 32x32 C/D map: col = lane&31, row = (reg&3) + 8*(reg>>2) + 4*(lane>>5)
  const int crow0 = bm + wr * 128 + 4 * lq2;
  const int ccol = bn + wc * 32 + l31;
  const float bv = bias[ccol];
#pragma unroll
  for (int i = 0; i < 4; ++i) {
#pragma unroll
    for (int reg = 0; reg < 16; ++reg) {
      const int row = crow0 + i * 32 + (reg & 3) + 8 * (reg >> 2);
      C[(size_t)row * N + ccol] = acc[i][reg] + bv;
    }
  }
}

// ---------------------------------------------------------------------------
// Fallback prepasses (linear layouts) for non-divisible shapes.
// ---------------------------------------------------------------------------
__global__ __launch_bounds__(256) void dequant_kernel(
    const int* __restrict__ qweight, const int* __restrict__ qzeros,
    const float* __restrict__ scales, short* __restrict__ Wt,
    int in_f, int out_f) {
  __shared__ __align__(16) short T[64][72];
  const int n0 = blockIdx.x * 64;
  const int k0 = blockIdx.y * 64;
  const int t = threadIdx.x;
  const int nl = t & 63;
  const int kw = t >> 6;
  const int n = n0 + nl;
  const int g = k0 >> 7;
  const float sc = scales[(size_t)g * out_f + n];
  const int zpw = qzeros[(size_t)g * (out_f >> 3) + (n >> 3)];
  const float zp = (float)(((zpw >> ((n & 7) * 4)) & 15) + 1);
  const float zs = zp * sc;
#pragma unroll
  for (int rr = 0; rr < 2; ++rr) {
    const int kwi = kw + rr * 4;
    const int w = qweight[(size_t)((k0 >> 3) + kwi) * out_f + n];
    short8 v;
#pragma unroll
    for (int e = 0; e < 8; ++e) {
      float f = (float)((w >> (4 * e)) & 15) * sc - zs;
      v[e] = f2bf(f);
    }
    *(short8*)&T[nl][kwi * 8] = v;
  }
  __syncthreads();
#pragma unroll
  for (int rr = 0; rr < 2; ++rr) {
    const int c = rr * 256 + t;
    const int row = c >> 3, ch = c & 7;
    *(short8*)&Wt[(size_t)(n0 + row) * in_f + k0 + ch * 8] =
        *(const short8*)&T[row][ch * 8];
  }
}

__global__ __launch_bounds__(256) void cvt_kernel(
    const float* __restrict__ x, short* __restrict__ xb, long n8) {
  long i = (long)blockIdx.x * blockDim.x + threadIdx.x;
  if (i >= n8) return;
  const float* src = x + i * 8;
  float4 a = *(const float4*)src;
  float4 b = *(const float4*)(src + 4);
  short8 v;
  v[0] = f2bf(a.x); v[1] = f2bf(a.y); v[2] = f2bf(a.z); v[3] = f2bf(a.w);
  v[4] = f2bf(b.x); v[5] = f2bf(b.y); v[6] = f2bf(b.z); v[7] = f2bf(b.w);
  *(short8*)(xb + i * 8) = v;
}

// ---------------------------------------------------------------------------
// 128x128x64 GEMM (fallback for non-divisible shapes).
// ---------------------------------------------------------------------------
#define BM 128
#define BN 128
#define BK 64

template <bool A_BF16>
__global__ __launch_bounds__(256) void gemm_bias_kernel(
    const void* __restrict__ Av, const short* __restrict__ Bt,
    const float* __restrict__ bias, float* __restrict__ C,
    int M, int N, int K) {
  __shared__ __align__(16) short As[BM * BK];
  __shared__ __align__(16) short Bs[BN * BK];
  const int tid = threadIdx.x;
  const int bm = blockIdx.y * BM;
  const int bn = blockIdx.x * BN;
  const int wid = tid >> 6, lane = tid & 63;
  const int wr = wid >> 1, wc = wid & 1;
  const int lrow = lane & 15;
  const int lk = (lane >> 4) * 8;

  f32x4 acc[4][4] = {};

  for (int kt = 0; kt < K; kt += BK) {
    if constexpr (A_BF16) {
      const short* A = (const short*)Av;
#pragma unroll
      for (int r = 0; r < 4; ++r) {
        const int c = r * 256 + tid;
        const int row = c >> 3, ch = c & 7;
        gload_lds16(A + (size_t)(bm + row) * K + kt + ch * 8,
                    (char*)As + c * 16);
      }
    } else {
      const float* A = (const float*)Av;
#pragma unroll
      for (int r = 0; r < 4; ++r) {
        const int c = r * 256 + tid;
        const int row = c >> 3, ch = c & 7;
        const float* src = A + (size_t)(bm + row) * K + kt + ch * 8;
        float4 f0 = *(const float4*)src;
        float4 f1 = *(const float4*)(src + 4);
        short8 v;
        v[0] = f2bf(f0.x); v[1] = f2bf(f0.y); v[2] = f2bf(f0.z); v[3] = f2bf(f0.w);
        v[4] = f2bf(f1.x); v[5] = f2bf(f1.y); v[6] = f2bf(f1.z); v[7] = f2bf(f1.w);
        *(short8*)((char*)As + c * 16) = v;
      }
    }
#pragma unroll
    for (int r = 0; r < 4; ++r) {
      const int c = r * 256 + tid;
      const int row = c >> 3, ch = c & 7;
      gload_lds16(Bt + (size_t)(bn + row) * K + kt + ch * 8,
                  (char*)Bs + c * 16);
    }
    __syncthreads();
#pragma unroll
    for (int kk = 0; kk < 2; ++kk) {
      short8 af[4], bf[4];
#pragma unroll
      for (int i = 0; i < 4; ++i)
        af[i] = *(const short8*)&As[(wr * 64 + i * 16 + lrow) * BK + kk * 32 + lk];
#pragma unroll
      for (int j = 0; j < 4; ++j)
        bf[j] = *(const short8*)&Bs[(wc * 64 + j * 16 + lrow) * BK + kk * 32 + lk];
#pragma unroll
      for (int i = 0; i < 4; ++i)
#pragma unroll
        for (int j = 0; j < 4; ++j)
          acc[i][j] = __builtin_amdgcn_mfma_f32_16x16x32_bf16(
              af[i], bf[j], acc[i][j], 0, 0, 0);
    }
    __syncthreads();
  }

  const int crow0 = bm + wr * 64 + (lane >> 4) * 4;
  const int ccol0 = bn + wc * 64 + (lane & 15);
#pragma unroll
  for (int j = 0; j < 4; ++j) {
    const float bv = bias[ccol0 + j * 16];
#pragma unroll
    for (int i = 0; i < 4; ++i) {
#pragma unroll
      for (int r = 0; r < 4; ++r) {
        C[(size_t)(crow0 + i * 16 + r) * N + ccol0 + j * 16] = acc[i][j][r] + bv;
      }
    }
  }
}

// ---------------------------------------------------------------------------
// Last-resort fallback: naive fused dequant GEMM.
// ---------------------------------------------------------------------------
__global__ __launch_bounds__(256) void naive_kernel(
    const float* __restrict__ x, const float* __restrict__ scales,
    const float* __restrict__ bias, const int* __restrict__ qw,
    const int* __restrict__ qz, float* __restrict__ out,
    int M, int K, int N) {
  long idx = (long)blockIdx.x * blockDim.x + threadIdx.x;
  if (idx >= (long)M * N) return;
  const int n = (int)(idx % N);
  const int m = (int)(idx / N);
  float acc = 0.f;
  for (int g = 0; g < K / 128; ++g) {
    const float sc = scales[(size_t)g * N + n];
    const float zp =
        (float)(((qz[(size_t)g * (N >> 3) + (n >> 3)] >> ((n & 7) * 4)) & 15) + 1);
    const float zs = zp * sc;
    for (int kw = 0; kw < 16; ++kw) {
      const int w = qw[(size_t)(g * 16 + kw) * N + n];
      const float* xp = &x[(size_t)m * K + g * 128 + kw * 8];
#pragma unroll
      for (int e = 0; e < 8; ++e)
        acc += xp[e] * ((float)((w >> (4 * e)) & 15) * sc - zs);
    }
  }
  out[idx] = acc + bias[n];
}

// ---------------------------------------------------------------------------
extern "C" void kernel_launch(void* const* d_in, const int* in_sizes, int n_in,
                              void* d_out, int out_size, void* d_ws,
                              size_t ws_size, hipStream_t stream) {
  const float* x = (const float*)d_in[0];
  const float* scales = (const float*)d_in[1];
  const float* bias = (const float*)d_in[2];
  const int* qweight = (const int*)d_in[3];
  const int* qzeros = (const int*)d_in[4];
  float* out = (float*)d_out;

  const int out_f = in_sizes[2];            // 12288
  const int kwords = in_sizes[3] / out_f;   // 512
  const int in_f = kwords * 8;              // 4096
  const int tokens = in_sizes[0] / in_f;    // 8192
  const int M = tokens, K = in_f, N = out_f;

  const size_t wt_bytes = (size_t)K * N * sizeof(short);
  const size_t xb_bytes = (size_t)M * K * sizeof(short);

  const bool div128 = (M % BM == 0) && (N % BN == 0) && (K % BK == 0) &&
                      (K % 128 == 0) && (N % 64 == 0);
  const bool divR17 = (M % GBM == 0) && (N % GBN == 0) && (K % 256 == 0) &&
                      (((K >> 5) - 2) % 3 == 0);

  if (divR17 && ws_size >= wt_bytes + xb_bytes) {
    // R17 pre-tiled path
    short* Btile = (short*)d_ws;                        // B' fragment tiles
    short* Atile = (short*)((char*)d_ws + wt_bytes);    // A' fragment tiles
    const int ktn = K >> 5;
    dequant_tile_kernel<<<(N / 128) * ktn, 256, 0, stream>>>(
        qweight, qzeros, scales, Btile, N, K);
    cvt_tile_kernel<<<(M / 256) * ktn, 256, 0, stream>>>(x, Atile, K);
    gemm256_kernel<<<(M / GBM) * (N / GBN), 512, 0, stream>>>(
        Atile, Btile, bias, out, M, N, K);
  } else if (div128 && ws_size >= wt_bytes + xb_bytes) {
    short* Wt = (short*)d_ws;
    short* xb = (short*)((char*)d_ws + wt_bytes);
    dequant_kernel<<<dim3(N / 64, K / 64), 256, 0, stream>>>(
        qweight, qzeros, scales, Wt, K, N);
    const long n8 = (long)M * K / 8;
    cvt_kernel<<<(int)((n8 + 255) / 256), 256, 0, stream>>>(x, xb, n8);
    gemm_bias_kernel<true><<<dim3(N / BN, M / BM), 256, 0, stream>>>(
        xb, Wt, bias, out, M, N, K);
  } else if (div128 && ws_size >= wt_bytes) {
    short* Wt = (short*)d_ws;
    dequant_kernel<<<dim3(N / 64, K / 64), 256, 0, stream>>>(
        qweight, qzeros, scales, Wt, K, N);
    gemm_bias_kernel<false><<<dim3(N / BN, M / BM), 256, 0, stream>>>(
        x, Wt, bias, out, M, N, K);
  } else {
    const long total = (long)M * N;
    naive_kernel<<<(int)((total + 255) / 256), 256, 0, stream>>>(
        x, scales, bias, qweight, qzeros, out, M, K, N);
  }
}

// Round 18
// 751.126 us; speedup vs baseline: 1.2053x; 1.2053x over previous
//
#include <hip/hip_runtime.h>
#include <hip/hip_bf16.h>

// ---------------------------------------------------------------------------
// WeightOnlyLinear: y = x @ dequant4(qweight, scales, qzeros) + bias
//   x (8192,4096) fp32 | scales (32,12288) | bias (12288) | qweight (512,12288)
//   qzeros (32,1536) | out (8192,12288) fp32
// R18: R16 co-resident structure (tile 256x128, ring-3 x 24KB LDS,
//   launch_bounds(512,4) -> 2 blocks/CU, 16x16x32 MFMA, vm3+bar per K-32
//   phase) with SQUARE WAVE TILES: 8 waves as 4M x 2N (wave 64x64,
//   acc[4][4]). Cuts LDS fragment-read amplification (A dup 4x->2x; total
//   per-block-phase LDS 104KB -> 88KB) now that co-residency (R16) made the
//   LDS pipe the binding resource. Prepasses = R16's verified 16-row-block
//   fragment-major maps, unchanged.
// ---------------------------------------------------------------------------

typedef __attribute__((ext_vector_type(8))) short short8;
typedef __attribute__((ext_vector_type(4))) float f32x4;

__device__ __forceinline__ short f2bf(float f) {
  unsigned u = __float_as_uint(f);
  u += 0x7fffu + ((u >> 16) & 1u);
  return (short)(u >> 16);
}

__device__ __forceinline__ void gload_lds16(const void* g, void* l) {
  __builtin_amdgcn_global_load_lds(
      (const __attribute__((address_space(1))) void*)g,
      (__attribute__((address_space(3))) void*)l,
      16, 0, 0);
}

__device__ __forceinline__ void bar() {
  asm volatile("" ::: "memory");
  __builtin_amdgcn_s_barrier();
  asm volatile("" ::: "memory");
}
__device__ __forceinline__ void wait_vm3() {
  asm volatile("s_waitcnt vmcnt(3)" ::: "memory");
}
__device__ __forceinline__ void wait_vm0() {
  asm volatile("s_waitcnt vmcnt(0)" ::: "memory");
}

// ---------------------------------------------------------------------------
// Pass 1 (R16 map): dequant qweight -> B' fragment-major (nb128, kt32) 8KB
// tiles. Chunk c (16B): cb=c>>6, l=c&63; col = nb*128 + cb*16 + (l&15);
// kw = kt*4 + (l>>4). One qweight word == one chunk.
// grid = (N/128)*(K/32), 256 thr, 2 chunks/thr.
// ---------------------------------------------------------------------------
__global__ __launch_bounds__(256) void dequant_tile_kernel(
    const int* __restrict__ qweight, const int* __restrict__ qzeros,
    const float* __restrict__ scales, short* __restrict__ Bt,
    int N, int K) {
  const int ktn = K >> 5;
  const int bx = blockIdx.x;
  const int nb = bx / ktn, kt = bx - nb * ktn;
  const int t = threadIdx.x;
  const int g = kt >> 2;  // GROUPSIZE=128 = 4 k32-tiles
  char* dst = (char*)Bt + (size_t)bx * 8192;
#pragma unroll
  for (int p = 0; p < 2; ++p) {
    const int c = p * 256 + t;
    const int l = c & 63;
    const int n = nb * 128 + (c >> 6) * 16 + (l & 15);
    const int kw = kt * 4 + (l >> 4);
    const float sc = scales[(size_t)g * N + n];
    const int zw = qzeros[(size_t)g * (N >> 3) + (n >> 3)];
    const float zs = -(float)(((zw >> ((n & 7) * 4)) & 15) + 1) * sc;
    const int w = qweight[(size_t)kw * N + n];
    short8 v;
#pragma unroll
    for (int e = 0; e < 8; ++e)
      v[e] = f2bf(fmaf((float)((w >> (4 * e)) & 15), sc, zs));
    *(short8*)(dst + c * 16) = v;
  }
}

// ---------------------------------------------------------------------------
// Pass 2 (R16 map): x fp32 -> A' fragment-major (mb256, kt32) 16KB tiles.
// Chunk c: rb=c>>6, l=c&63; row = mb*256 + rb*16 + (l&15); k = kt*32+(l>>4)*8.
// grid = (M/256)*(K/32), 256 thr, 4 chunks/thr.
// ---------------------------------------------------------------------------
__global__ __launch_bounds__(256) void cvt_tile_kernel(
    const float* __restrict__ x, short* __restrict__ xb, int K) {
  const int ktn = K >> 5;
  const int bx = blockIdx.x;
  const int mb = bx / ktn, kt = bx - mb * ktn;
  char* dst = (char*)xb + (size_t)bx * 16384;
#pragma unroll
  for (int p = 0; p < 4; ++p) {
    const int c = p * 256 + threadIdx.x;
    const int l = c & 63;
    const int row = mb * 256 + (c >> 6) * 16 + (l & 15);
    const int k = kt * 32 + (l >> 4) * 8;
    const float* s = x + (size_t)row * K + k;
    float4 f0 = *(const float4*)s;
    float4 f1 = *(const float4*)(s + 4);
    short8 v;
    v[0] = f2bf(f0.x); v[1] = f2bf(f0.y); v[2] = f2bf(f0.z); v[3] = f2bf(f0.w);
    v[4] = f2bf(f1.x); v[5] = f2bf(f1.y); v[6] = f2bf(f1.z); v[7] = f2bf(f1.w);
    *(short8*)(dst + c * 16) = v;
  }
}

// ---------------------------------------------------------------------------
// Pass 3 (R18): 256x128 GEMM, 512 threads = 8 waves as 4M x 2N, wave 64x64.
// MFMA 16x16x32; acc f32x4[4][4]. LDS: ring-3 x 24576 (A 16KB @0, B 8KB
// @16384), fragment-major. Phase q (slot q%3): {vm3; bar; 8 frag reads;
// stage tile q+2 -> slot (q+2)%3 [3 gloads]; setprio 16 MFMA}.
// Tail peel: vm3 / vm0.
// ---------------------------------------------------------------------------
#define GBM 256
#define GBN 128

__global__ __launch_bounds__(512, 4) void gemm256_kernel(
    const short* __restrict__ At, const short* __restrict__ Bt,
    const float* __restrict__ bias, float* __restrict__ C,
    int M, int N, int K) {
  __shared__ __align__(16) char lds[3 * 24576];
  const int tid = threadIdx.x;
  const int nbx = N / GBN;
  const int nwg = gridDim.x;
  int bid = blockIdx.x;
  if ((nwg & 7) == 0) bid = (bid & 7) * (nwg >> 3) + (bid >> 3);  // T1
  const int mb = bid / nbx;
  const int nb = bid % nbx;
  const int bm = mb * GBM, bn = nb * GBN;

  const int wid = tid >> 6, lane = tid & 63;
  const int wr = wid >> 1, wc = wid & 1;  // 4M x 2N wave grid

  const int P = K >> 5;  // K-32 tiles; launcher guarantees (P-2)%3==0

  char* lb = &lds[0];

  // frag read bases: A frag i (rows wr*64 + i*16) at
  //   SL*24576 + (wr*4+i)*1024 + lane*16;
  // B frag j (cols wc*64 + j*16) at 16384 + SL*24576 + (wc*4+j)*1024 + lane*16.
  const char* aBase = lb + wr * 4096 + lane * 16;
  const char* bBase = lb + 16384 + wc * 4096 + lane * 16;

  // staging: A chunks {tid, tid+512}, B chunk {tid}; linear dst
  const char* pA = (const char*)At + (size_t)mb * P * 16384 + (size_t)tid * 16;
  const char* pB = (const char*)Bt + (size_t)nb * P * 8192 + (size_t)tid * 16;
  char* dA = lb + tid * 16;
  char* dB = lb + 16384 + tid * 16;

#define STAGE(TSL, AOFF, BOFF)                                \
  do {                                                        \
    gload_lds16(pA + (AOFF), dA + (TSL)*24576);               \
    gload_lds16(pA + (AOFF) + 8192, dA + (TSL)*24576 + 8192); \
    gload_lds16(pB + (BOFF), dB + (TSL)*24576);               \
  } while (0)

  short8 aR[4], bR[4];

#define RD(SL)                                                        \
  do {                                                                \
    _Pragma("unroll") for (int i = 0; i < 4; ++i) aR[i] =             \
        *(const short8*)(aBase + (SL)*24576 + i * 1024);              \
    _Pragma("unroll") for (int j = 0; j < 4; ++j) bR[j] =             \
        *(const short8*)(bBase + (SL)*24576 + j * 1024);              \
  } while (0)

  f32x4 acc[4][4] = {};

#define MFMA16()                                                         \
  do {                                                                   \
    __builtin_amdgcn_s_setprio(1);                                       \
    _Pragma("unroll") for (int i = 0; i < 4; ++i)                        \
        _Pragma("unroll") for (int j = 0; j < 4; ++j) acc[i][j] =        \
            __builtin_amdgcn_mfma_f32_16x16x32_bf16(aR[i], bR[j],        \
                                                    acc[i][j], 0, 0, 0); \
    __builtin_amdgcn_s_setprio(0);                                       \
  } while (0)

  // prologue: tile0 -> slot0, tile1 -> slot1 (6 gloads)
  STAGE(0, 0, 0);
  STAGE(1, 16384, 8192);

  // body: (P-2)/3 iterations x 3 phases; phase q stages tile q+2.
  const int nIt = (P - 2) / 3;
  for (int it = 0; it < nIt; ++it) {
    wait_vm3(); bar();
    RD(0); STAGE(2, 2 * 16384, 2 * 8192); MFMA16();
    wait_vm3(); bar();
    RD(1); STAGE(0, 3 * 16384, 3 * 8192); MFMA16();
    wait_vm3(); bar();
    RD(2); STAGE(1, 4 * 16384, 4 * 8192); MFMA16();
    pA += 3 * 16384;
    pB += 3 * 8192;
  }
  // peel: q = P-2 (slot 0), q = P-1 (slot 1)
  wait_vm3(); bar();
  RD(0); MFMA16();
  wait_vm0(); bar();
  RD(1); MFMA16();

#undef MFMA16
#undef RD
#undef STAGE

  // epilogue: C = acc + bias. 16x16 C/D: col=lane&15, row=(lane>>4)*4+r
  const int crow0 = bm + wr * 64 + (lane >> 4) * 4;
  const int ccol0 = bn + wc * 64 + (lane & 15);
#pragma unroll
  for (int fj = 0; fj < 4; ++fj) {
    const float bv = bias[ccol0 + fj * 16];
#pragma unroll
    for (int fi = 0; fi < 4; ++fi) {
#pragma unroll
      for (int r = 0; r < 4; ++r) {
        C[(size_t)(crow0 + fi * 16 + r) * N + ccol0 + fj * 16] =
            acc[fi][fj][r] + bv;
      }
    }
  }
}

// ---------------------------------------------------------------------------
// Fallback prepasses (linear layouts) for non-divisible shapes.
// ---------------------------------------------------------------------------
__global__ __launch_bounds__(256) void dequant_kernel(
    const int* __restrict__ qweight, const int* __restrict__ qzeros,
    const float* __restrict__ scales, short* __restrict__ Wt,
    int in_f, int out_f) {
  __shared__ __align__(16) short T[64][72];
  const int n0 = blockIdx.x * 64;
  const int k0 = blockIdx.y * 64;
  const int t = threadIdx.x;
  const int nl = t & 63;
  const int kw = t >> 6;
  const int n = n0 + nl;
  const int g = k0 >> 7;
  const float sc = scales[(size_t)g * out_f + n];
  const int zpw = qzeros[(size_t)g * (out_f >> 3) + (n >> 3)];
  const float zp = (float)(((zpw >> ((n & 7) * 4)) & 15) + 1);
  const float zs = zp * sc;
#pragma unroll
  for (int rr = 0; rr < 2; ++rr) {
    const int kwi = kw + rr * 4;
    const int w = qweight[(size_t)((k0 >> 3) + kwi) * out_f + n];
    short8 v;
#pragma unroll
    for (int e = 0; e < 8; ++e) {
      float f = (float)((w >> (4 * e)) & 15) * sc - zs;
      v[e] = f2bf(f);
    }
    *(short8*)&T[nl][kwi * 8] = v;
  }
  __syncthreads();
#pragma unroll
  for (int rr = 0; rr < 2; ++rr) {
    const int c = rr * 256 + t;
    const int row = c >> 3, ch = c & 7;
    *(short8*)&Wt[(size_t)(n0 + row) * in_f + k0 + ch * 8] =
        *(const short8*)&T[row][ch * 8];
  }
}

__global__ __launch_bounds__(256) void cvt_kernel(
    const float* __restrict__ x, short* __restrict__ xb, long n8) {
  long i = (long)blockIdx.x * blockDim.x + threadIdx.x;
  if (i >= n8) return;
  const float* src = x + i * 8;
  float4 a = *(const float4*)src;
  float4 b = *(const float4*)(src + 4);
  short8 v;
  v[0] = f2bf(a.x); v[1] = f2bf(a.y); v[2] = f2bf(a.z); v[3] = f2bf(a.w);
  v[4] = f2bf(b.x); v[5] = f2bf(b.y); v[6] = f2bf(b.z); v[7] = f2bf(b.w);
  *(short8*)(xb + i * 8) = v;
}

// ---------------------------------------------------------------------------
// 128x128x64 GEMM (fallback for non-divisible shapes).
// ---------------------------------------------------------------------------
#define BM 128
#define BN 128
#define BK 64

template <bool A_BF16>
__global__ __launch_bounds__(256) void gemm_bias_kernel(
    const void* __restrict__ Av, const short* __restrict__ Bt,
    const float* __restrict__ bias, float* __restrict__ C,
    int M, int N, int K) {
  __shared__ __align__(16) short As[BM * BK];
  __shared__ __align__(16) short Bs[BN * BK];
  const int tid = threadIdx.x;
  const int bm = blockIdx.y * BM;
  const int bn = blockIdx.x * BN;
  const int wid = tid >> 6, lane = tid & 63;
  const int wr = wid >> 1, wc = wid & 1;
  const int lrow = lane & 15;
  const int lk = (lane >> 4) * 8;

  f32x4 acc[4][4] = {};

  for (int kt = 0; kt < K; kt += BK) {
    if constexpr (A_BF16) {
      const short* A = (const short*)Av;
#pragma unroll
      for (int r = 0; r < 4; ++r) {
        const int c = r * 256 + tid;
        const int row = c >> 3, ch = c & 7;
        gload_lds16(A + (size_t)(bm + row) * K + kt + ch * 8,
                    (char*)As + c * 16);
      }
    } else {
      const float* A = (const float*)Av;
#pragma unroll
      for (int r = 0; r < 4; ++r) {
        const int c = r * 256 + tid;
        const int row = c >> 3, ch = c & 7;
        const float* src = A + (size_t)(bm + row) * K + kt + ch * 8;
        float4 f0 = *(const float4*)src;
        float4 f1 = *(const float4*)(src + 4);
        short8 v;
        v[0] = f2bf(f0.x); v[1] = f2bf(f0.y); v[2] = f2bf(f0.z); v[3] = f2bf(f0.w);
        v[4] = f2bf(f1.x); v[5] = f2bf(f1.y); v[6] = f2bf(f1.z); v[7] = f2bf(f1.w);
        *(short8*)((char*)As + c * 16) = v;
      }
    }
#pragma unroll
    for (int r = 0; r < 4; ++r) {
      const int c = r * 256 + tid;
      const int row = c >> 3, ch = c & 7;
      gload_lds16(Bt + (size_t)(bn + row) * K + kt + ch * 8,
                  (char*)Bs + c * 16);
    }
    __syncthreads();
#pragma unroll
    for (int kk = 0; kk < 2; ++kk) {
      short8 af[4], bf[4];
#pragma unroll
      for (int i = 0; i < 4; ++i)
        af[i] = *(const short8*)&As[(wr * 64 + i * 16 + lrow) * BK + kk * 32 + lk];
#pragma unroll
      for (int j = 0; j < 4; ++j)
        bf[j] = *(const short8*)&Bs[(wc * 64 + j * 16 + lrow) * BK + kk * 32 + lk];
#pragma unroll
      for (int i = 0; i < 4; ++i)
#pragma unroll
        for (int j = 0; j < 4; ++j)
          acc[i][j] = __builtin_amdgcn_mfma_f32_16x16x32_bf16(
              af[i], bf[j], acc[i][j], 0, 0, 0);
    }
    __syncthreads();
  }

  const int crow0 = bm + wr * 64 + (lane >> 4) * 4;
  const int ccol0 = bn + wc * 64 + (lane & 15);
#pragma unroll
  for (int j = 0; j < 4; ++j) {
    const float bv = bias[ccol0 + j * 16];
#pragma unroll
    for (int i = 0; i < 4; ++i) {
#pragma unroll
      for (int r = 0; r < 4; ++r) {
        C[(size_t)(crow0 + i * 16 + r) * N + ccol0 + j * 16] = acc[i][j][r] + bv;
      }
    }
  }
}

// ---------------------------------------------------------------------------
// Last-resort fallback: naive fused dequant GEMM.
// ---------------------------------------------------------------------------
__global__ __launch_bounds__(256) void naive_kernel(
    const float* __restrict__ x, const float* __restrict__ scales,
    const float* __restrict__ bias, const int* __restrict__ qw,
    const int* __restrict__ qz, float* __restrict__ out,
    int M, int K, int N) {
  long idx = (long)blockIdx.x * blockDim.x + threadIdx.x;
  if (idx >= (long)M * N) return;
  const int n = (int)(idx % N);
  const int m = (int)(idx / N);
  float acc = 0.f;
  for (int g = 0; g < K / 128; ++g) {
    const float sc = scales[(size_t)g * N + n];
    const float zp =
        (float)(((qz[(size_t)g * (N >> 3) + (n >> 3)] >> ((n & 7) * 4)) & 15) + 1);
    const float zs = zp * sc;
    for (int kw = 0; kw < 16; ++kw) {
      const int w = qw[(size_t)(g * 16 + kw) * N + n];
      const float* xp = &x[(size_t)m * K + g * 128 + kw * 8];
#pragma unroll
      for (int e = 0; e < 8; ++e)
        acc += xp[e] * ((float)((w >> (4 * e)) & 15) * sc - zs);
    }
  }
  out[idx] = acc + bias[n];
}

// ---------------------------------------------------------------------------
extern "C" void kernel_launch(void* const* d_in, const int* in_sizes, int n_in,
                              void* d_out, int out_size, void* d_ws,
                              size_t ws_size, hipStream_t stream) {
  const float* x = (const float*)d_in[0];
  const float* scales = (const float*)d_in[1];
  const float* bias = (const float*)d_in[2];
  const int* qweight = (const int*)d_in[3];
  const int* qzeros = (const int*)d_in[4];
  float* out = (float*)d_out;

  const int out_f = in_sizes[2];            // 12288
  const int kwords = in_sizes[3] / out_f;   // 512
  const int in_f = kwords * 8;              // 4096
  const int tokens = in_sizes[0] / in_f;    // 8192
  const int M = tokens, K = in_f, N = out_f;

  const size_t wt_bytes = (size_t)K * N * sizeof(short);
  const size_t xb_bytes = (size_t)M * K * sizeof(short);

  const bool div128 = (M % BM == 0) && (N % BN == 0) && (K % BK == 0) &&
                      (K % 128 == 0) && (N % 64 == 0);
  const bool divR18 = (M % GBM == 0) && (N % GBN == 0) && (K % 256 == 0) &&
                      (((K >> 5) - 2) % 3 == 0);

  if (divR18 && ws_size >= wt_bytes + xb_bytes) {
    // R18 pre-tiled path
    short* Btile = (short*)d_ws;                        // B' fragment tiles
    short* Atile = (short*)((char*)d_ws + wt_bytes);    // A' fragment tiles
    const int ktn = K >> 5;
    dequant_tile_kernel<<<(N / 128) * ktn, 256, 0, stream>>>(
        qweight, qzeros, scales, Btile, N, K);
    cvt_tile_kernel<<<(M / 256) * ktn, 256, 0, stream>>>(x, Atile, K);
    gemm256_kernel<<<(M / GBM) * (N / GBN), 512, 0, stream>>>(
        Atile, Btile, bias, out, M, N, K);
  } else if (div128 && ws_size >= wt_bytes + xb_bytes) {
    short* Wt = (short*)d_ws;
    short* xb = (short*)((char*)d_ws + wt_bytes);
    dequant_kernel<<<dim3(N / 64, K / 64), 256, 0, stream>>>(
        qweight, qzeros, scales, Wt, K, N);
    const long n8 = (long)M * K / 8;
    cvt_kernel<<<(int)((n8 + 255) / 256), 256, 0, stream>>>(x, xb, n8);
    gemm_bias_kernel<true><<<dim3(N / BN, M / BM), 256, 0, stream>>>(
        xb, Wt, bias, out, M, N, K);
  } else if (div128 && ws_size >= wt_bytes) {
    short* Wt = (short*)d_ws;
    dequant_kernel<<<dim3(N / 64, K / 64), 256, 0, stream>>>(
        qweight, qzeros, scales, Wt, K, N);
    gemm_bias_kernel<false><<<dim3(N / BN, M / BM), 256, 0, stream>>>(
        x, Wt, bias, out, M, N, K);
  } else {
    const long total = (long)M * N;
    naive_kernel<<<(int)((total + 255) / 256), 256, 0, stream>>>(
        x, scales, bias, qweight, qzeros, out, M, K, N);
  }
}